// Round 1
// baseline (295.390 us; speedup 1.0000x reference)
//
#include <hip/hip_runtime.h>
#include <math.h>

// Problem constants
#define BATCH 256
#define CIN   3
#define COUT  16
#define DI    16
#define HI    32
#define WI    32
// Needed conv region per pd-slice: local od 0..3 (global 4*pd+od), oh 0..27, ow 0..27
// Pool: 4x4x4 stride 4 -> out [256,16,3,7,7]

#define XROWS (CIN*6*30)   // cin * dplanes(6) * h(30)
#define XSTR  36           // padded row stride (floats): 36*4B=144B, 16B-aligned, 36%32!=0

// ---------------------------------------------------------------------------
// Tiny pre-pass: transpose W[16][3][3][3][3] -> wt[27][48] where
// wt[(cin*3+kd)*3+kh][c*3+kw] = W[c][cin][kd][kh][kw]
// Contiguous 48-float rows -> wave-uniform s_load_dwordx16 in the main kernel.
// ---------------------------------------------------------------------------
__global__ void wt_transpose(const float* __restrict__ W, float* __restrict__ wt) {
    int idx = blockIdx.x * 256 + threadIdx.x;
    if (idx < COUT * 81) {
        int c = idx / 81, r = idx % 81;
        int cin = r / 27, kd = (r / 9) % 3, kh = (r / 3) % 3, kw = r % 3;
        wt[((cin*3 + kd)*3 + kh)*48 + c*3 + kw] = W[idx];
    }
}

// ---------------------------------------------------------------------------
// Main fused kernel: conv3d + bias + channel-softmax + 4x4x4 maxpool.
// One WG per (b, pd). 256 threads; each thread handles blocks of 4 consecutive
// ow (exactly one pool cell in w) for all 16 output channels.
// ---------------------------------------------------------------------------
__global__ __launch_bounds__(256, 1) void conv_sm_pool(
    const float* __restrict__ x, const float* __restrict__ wt,
    const float* __restrict__ bias, float* __restrict__ out)
{
    __shared__ float xs[XROWS * XSTR];            // 540*36*4 = 77760 B
    __shared__ float partials[4*28*7*16];         // 50176 B   (total ~125 KB LDS)

    const int tid = threadIdx.x;
    const int b   = blockIdx.x / 3;
    const int pd  = blockIdx.x % 3;
    const int d0  = pd * 4;

    // ---- Phase A: stage x[b, :, d0..d0+5, 0..29, 0..31] into LDS (float4) ----
    for (int i = tid; i < CIN*6*30*8; i += 256) {
        int q   = i & 7;          // which float4 within the 32-wide row
        int row = i >> 3;
        int hh  = row % 30;
        int rd  = row / 30;
        int dd  = rd % 6;
        int cin = rd / 6;
        const float4 v = *(const float4*)(
            x + (((size_t)(b*CIN + cin)*DI + (d0 + dd))*HI + hh)*WI + q*4);
        *(float4*)(xs + ((cin*6 + dd)*30 + hh)*XSTR + q*4) = v;
    }

    // bias is wave-uniform -> scalar loads
    float bv[COUT];
    #pragma unroll
    for (int c = 0; c < COUT; ++c) bv[c] = bias[c];

    __syncthreads();

    // ---- Phase B: conv + softmax + per-thread pool partial ----
    // 784 blocks: (d in 0..3) x (h in 0..27) x (wb in 0..6), w0 = 4*wb
    for (int blk = tid; blk < 784; blk += 256) {
        int d  = blk / 196;
        int r  = blk % 196;
        int h  = r / 7;
        int wb = r % 7;
        int w0 = wb * 4;

        float acc[COUT][4];
        #pragma unroll
        for (int c = 0; c < COUT; ++c) {
            acc[c][0] = 0.f; acc[c][1] = 0.f; acc[c][2] = 0.f; acc[c][3] = 0.f;
        }

        for (int cin = 0; cin < CIN; ++cin) {
            #pragma unroll
            for (int kd = 0; kd < 3; ++kd) {
                #pragma unroll
                for (int kh = 0; kh < 3; ++kh) {
                    const float* xr = xs + ((cin*6 + d + kd)*30 + h + kh)*XSTR + w0;
                    float4 xa = *(const float4*)xr;       // ds_read_b128
                    float2 xb = *(const float2*)(xr + 4); // ds_read_b64
                    float xv0 = xa.x, xv1 = xa.y, xv2 = xa.z,
                          xv3 = xa.w, xv4 = xb.x, xv5 = xb.y;
                    const float* wr = wt + ((cin*3 + kd)*3 + kh)*48;
                    #pragma unroll
                    for (int c = 0; c < COUT; ++c) {
                        float wa = wr[c*3], wbt = wr[c*3+1], wc = wr[c*3+2];
                        acc[c][0] = fmaf(wa, xv0, acc[c][0]);
                        acc[c][0] = fmaf(wbt, xv1, acc[c][0]);
                        acc[c][0] = fmaf(wc, xv2, acc[c][0]);
                        acc[c][1] = fmaf(wa, xv1, acc[c][1]);
                        acc[c][1] = fmaf(wbt, xv2, acc[c][1]);
                        acc[c][1] = fmaf(wc, xv3, acc[c][1]);
                        acc[c][2] = fmaf(wa, xv2, acc[c][2]);
                        acc[c][2] = fmaf(wbt, xv3, acc[c][2]);
                        acc[c][2] = fmaf(wc, xv4, acc[c][2]);
                        acc[c][3] = fmaf(wa, xv3, acc[c][3]);
                        acc[c][3] = fmaf(wbt, xv4, acc[c][3]);
                        acc[c][3] = fmaf(wc, xv5, acc[c][3]);
                    }
                }
            }
        }

        // softmax over channels per position, then max over the 4 w's
        float pm[COUT];
        #pragma unroll
        for (int c = 0; c < COUT; ++c) pm[c] = 0.f;

        #pragma unroll
        for (int p = 0; p < 4; ++p) {
            float m = -1e30f;
            #pragma unroll
            for (int c = 0; c < COUT; ++c) m = fmaxf(m, acc[c][p] + bv[c]);
            float e[COUT];
            float s = 0.f;
            #pragma unroll
            for (int c = 0; c < COUT; ++c) {
                e[c] = __expf(acc[c][p] + bv[c] - m);
                s += e[c];
            }
            float inv = 1.0f / s;
            #pragma unroll
            for (int c = 0; c < COUT; ++c) pm[c] = fmaxf(pm[c], e[c] * inv);
        }

        #pragma unroll
        for (int c = 0; c < COUT; ++c)
            partials[((d*28 + h)*7 + wb)*16 + c] = pm[c];
    }

    __syncthreads();

    // ---- Phase C: reduce partials over (d, h-in-pool) and write output ----
    // out[b][c][pd][ph][pw], 16*7*7 = 784 cells per WG
    for (int cell = tid; cell < 784; cell += 256) {
        int c  = cell / 49;
        int r2 = cell % 49;
        int ph = r2 / 7;
        int pw = r2 % 7;
        float v = 0.f;
        #pragma unroll
        for (int dq = 0; dq < 4; ++dq) {
            #pragma unroll
            for (int hq = 0; hq < 4; ++hq) {
                v = fmaxf(v, partials[((dq*28 + (ph*4 + hq))*7 + pw)*16 + c]);
            }
        }
        out[(((size_t)b*COUT + c)*3 + pd)*49 + r2] = v;
    }
}

extern "C" void kernel_launch(void* const* d_in, const int* in_sizes, int n_in,
                              void* d_out, int out_size, void* d_ws, size_t ws_size,
                              hipStream_t stream) {
    const float* x = (const float*)d_in[0];
    const float* W = (const float*)d_in[1];
    const float* bias = (const float*)d_in[2];
    float* out = (float*)d_out;
    float* wt = (float*)d_ws;   // 27*48 floats = 5184 B

    wt_transpose<<<6, 256, 0, stream>>>(W, wt);
    conv_sm_pool<<<BATCH * 3, 256, 0, stream>>>(x, wt, bias, out);
}

// Round 2
// 102.756 us; speedup vs baseline: 2.8747x; 2.8747x over previous
//
#include <hip/hip_runtime.h>
#include <math.h>

// Problem constants
#define BATCH 256
#define CIN   3
#define COUT  16
#define DI    16
#define HI    32
#define WI    32
// Output after conv(valid)+softmax(ch)+4^3 maxpool: [256,16,3,7,7]

#define XROWS (CIN*6*30)   // 540 rows staged per (b,pd)
#define XSTR  36           // padded row stride in floats (144B, 16B-aligned, !=0 mod 32)
#define PSTR  20           // partials stride in floats (80B, 16B-aligned, 5*blk%8 covers all quads)

// ---------------------------------------------------------------------------
// Pre-pass: W[16][3][3][3][3] -> wt[27][48], wt[(cin*3+kd)*3+kh][c*3+kw]
// Rows are wave-uniform in the main kernel -> scalar loads.
// ---------------------------------------------------------------------------
__global__ void wt_transpose(const float* __restrict__ W, float* __restrict__ wt) {
    int idx = blockIdx.x * 256 + threadIdx.x;
    if (idx < COUT * 81) {
        int c = idx / 81, r = idx % 81;
        int cin = r / 27, kd = (r / 9) % 3, kh = (r / 3) % 3, kw = r % 3;
        wt[((cin*3 + kd)*3 + kh)*48 + c*3 + kw] = W[idx];
    }
}

// ---------------------------------------------------------------------------
// Fused conv3d + bias + channel-softmax + 4x4x4 maxpool.
// One WG per (b, pd). 256 threads. Thread (h,wb) owns output row h, w-block wb
// (4 consecutive ow = one pool cell in w) and accumulates the pool max over
// the 4 d-slices IN REGISTERS (d-major loop). partials then only needs the
// h-reduction and aliases into the x-staging buffer -> 77.8 KB LDS, 2 WG/CU.
// ---------------------------------------------------------------------------
__global__ __launch_bounds__(256, 2) void conv_sm_pool(
    const float* __restrict__ x, const float* __restrict__ wt,
    const float* __restrict__ bias, float* __restrict__ out)
{
    __shared__ float smem[XROWS * XSTR];          // 19440 floats = 77760 B

    const int tid = threadIdx.x;
    const int b   = blockIdx.x / 3;
    const int pd  = blockIdx.x % 3;
    const int d0  = pd * 4;

    // ---- Phase A: stage x[b, :, d0..d0+5, 0..29, 0..31] into LDS (float4) ----
    for (int i = tid; i < CIN*6*30*8; i += 256) {
        int q   = i & 7;
        int row = i >> 3;
        int hh  = row % 30;
        int rd  = row / 30;
        int dd  = rd % 6;
        int cin = rd / 6;
        const float4 v = *(const float4*)(
            x + (((size_t)(b*CIN + cin)*DI + (d0 + dd))*HI + hh)*WI + q*4);
        *(float4*)(smem + ((cin*6 + dd)*30 + hh)*XSTR + q*4) = v;
    }

    float bv[COUT];
    #pragma unroll
    for (int c = 0; c < COUT; ++c) bv[c] = bias[c];

    __syncthreads();

    // ---- Phase B: d-major conv + softmax; pool-over-d in registers ----
    const bool active = (tid < 196);
    const int h  = tid / 7;       // 0..27
    const int wb = tid % 7;       // 0..6
    const int w0 = wb * 4;

    float pm[COUT];
    #pragma unroll
    for (int c = 0; c < COUT; ++c) pm[c] = 0.f;

    if (active) {
        for (int d = 0; d < 4; ++d) {
            float acc[COUT][4];
            #pragma unroll
            for (int c = 0; c < COUT; ++c) {
                acc[c][0] = 0.f; acc[c][1] = 0.f; acc[c][2] = 0.f; acc[c][3] = 0.f;
            }

            for (int cin = 0; cin < CIN; ++cin) {
                #pragma unroll
                for (int kd = 0; kd < 3; ++kd) {
                    #pragma unroll
                    for (int kh = 0; kh < 3; ++kh) {
                        const float* xr = smem + ((cin*6 + d + kd)*30 + h + kh)*XSTR + w0;
                        float4 xa = *(const float4*)xr;        // ds_read_b128
                        float2 xb = *(const float2*)(xr + 4);  // ds_read_b64
                        float xv0 = xa.x, xv1 = xa.y, xv2 = xa.z,
                              xv3 = xa.w, xv4 = xb.x, xv5 = xb.y;
                        const float* wr = wt + ((cin*3 + kd)*3 + kh)*48;
                        #pragma unroll
                        for (int c = 0; c < COUT; ++c) {
                            float wa = wr[c*3], wbt = wr[c*3+1], wc = wr[c*3+2];
                            acc[c][0] = fmaf(wa, xv0, acc[c][0]);
                            acc[c][0] = fmaf(wbt, xv1, acc[c][0]);
                            acc[c][0] = fmaf(wc, xv2, acc[c][0]);
                            acc[c][1] = fmaf(wa, xv1, acc[c][1]);
                            acc[c][1] = fmaf(wbt, xv2, acc[c][1]);
                            acc[c][1] = fmaf(wc, xv3, acc[c][1]);
                            acc[c][2] = fmaf(wa, xv2, acc[c][2]);
                            acc[c][2] = fmaf(wbt, xv3, acc[c][2]);
                            acc[c][2] = fmaf(wc, xv4, acc[c][2]);
                            acc[c][3] = fmaf(wa, xv3, acc[c][3]);
                            acc[c][3] = fmaf(wbt, xv4, acc[c][3]);
                            acc[c][3] = fmaf(wc, xv5, acc[c][3]);
                        }
                    }
                }
            }

            // softmax per position, fold into running pool max
            #pragma unroll
            for (int p = 0; p < 4; ++p) {
                float t[COUT];
                float m = -1e30f;
                #pragma unroll
                for (int c = 0; c < COUT; ++c) {
                    t[c] = acc[c][p] + bv[c];
                    m = fmaxf(m, t[c]);
                }
                float s = 0.f;
                #pragma unroll
                for (int c = 0; c < COUT; ++c) {
                    t[c] = __expf(t[c] - m);
                    s += t[c];
                }
                float inv = __builtin_amdgcn_rcpf(s);
                #pragma unroll
                for (int c = 0; c < COUT; ++c) pm[c] = fmaxf(pm[c], t[c] * inv);
            }
        }
    }

    __syncthreads();   // xs no longer needed; reuse smem for partials

    // ---- Phase B2: write pool partials (h-reduction pending) ----
    if (active) {
        #pragma unroll
        for (int q = 0; q < 4; ++q) {
            *(float4*)(smem + tid*PSTR + q*4) =
                make_float4(pm[q*4+0], pm[q*4+1], pm[q*4+2], pm[q*4+3]);
        }
    }

    __syncthreads();

    // ---- Phase C: reduce over hq, write out[b][c][pd][ph][pw] ----
    // cell = c (fastest, 16) x (ph,pw) (49) -> 784 cells
    for (int cell = tid; cell < 784; cell += 256) {
        int c   = cell & 15;
        int idx = cell >> 4;      // 0..48
        int ph  = idx / 7;
        int pw  = idx % 7;
        float v = 0.f;
        #pragma unroll
        for (int hq = 0; hq < 4; ++hq) {
            v = fmaxf(v, smem[((ph*4 + hq)*7 + pw)*PSTR + c]);
        }
        out[(((size_t)b*COUT + c)*3 + pd)*49 + idx] = v;
    }
}

extern "C" void kernel_launch(void* const* d_in, const int* in_sizes, int n_in,
                              void* d_out, int out_size, void* d_ws, size_t ws_size,
                              hipStream_t stream) {
    const float* x = (const float*)d_in[0];
    const float* W = (const float*)d_in[1];
    const float* bias = (const float*)d_in[2];
    float* out = (float*)d_out;
    float* wt = (float*)d_ws;   // 27*48 floats = 5184 B

    wt_transpose<<<6, 256, 0, stream>>>(W, wt);
    conv_sm_pool<<<BATCH * 3, 256, 0, stream>>>(x, wt, bias, out);
}

// Round 3
// 66.484 us; speedup vs baseline: 4.4430x; 1.5456x over previous
//
#include <hip/hip_runtime.h>
#include <math.h>

#define BATCH 256
#define CIN   3
#define COUT  16
#define DI    16
#define HI    32
#define WI    32

typedef _Float16 f16x8 __attribute__((ext_vector_type(8)));
typedef float    f32x4 __attribute__((ext_vector_type(4)));
static_assert(sizeof(f16x8) == 16, "f16x8 must be 16B");

// ---------------------------------------------------------------------------
// Prep: W[16][3][3][3][3] fp32 -> wtf[kw][lane][j] f16 MFMA A-fragments.
// A-operand (M=cout rows x K=32): lane l holds A[row=l&15][k=8*(l>>4)+j].
// k = cin*9 + kd*3 + kh; k>=27 zero-padded.
// ---------------------------------------------------------------------------
__global__ void prep(const float* __restrict__ W, unsigned short* __restrict__ wtf) {
    int e = blockIdx.x * 256 + threadIdx.x;      // 3*64*8 = 1536 tasks
    if (e < 3 * 64 * 8) {
        int kw = e >> 9;
        int l  = (e >> 3) & 63;
        int j  = e & 7;
        int c  = l & 15;
        int k  = ((l >> 4) << 3) + j;
        float v = 0.f;
        if (k < 27) {
            int cin = k / 9, kd = (k % 9) / 3, kh = k % 3;
            v = W[(((c * CIN + cin) * 3 + kd) * 3 + kh) * 3 + kw];
        }
        _Float16 h = (_Float16)v;
        wtf[(kw * 64 + l) * 8 + j] = __builtin_bit_cast(unsigned short, h);
    }
}

// ---------------------------------------------------------------------------
// Fused conv3d+bias+channel-softmax+4^3 maxpool via f16 implicit-GEMM MFMA.
// One WG per (b, pd); 768 WGs = 3 WG/CU x 256 CUs (all resident).
// LDS (ushort units):
//   xs   [0     , 19440): 540 rows x 36 hw, f16 x-slab (cin,dd 0..5, hh 0..29)x32w
//   im   [19440 , 24640): 130 rows x 40 hw, im2col tile: rows=(h_loc*32+w'), K=27 pad 32
//   part [24640 , 25920): [8 tiles][4 pw_loc][20] f32 pool partials
// ---------------------------------------------------------------------------
__global__ __launch_bounds__(256) void conv_sm_pool_mfma(
    const float* __restrict__ x, const unsigned short* __restrict__ wtf,
    const float* __restrict__ bias, float* __restrict__ out)
{
    __shared__ __align__(16) unsigned short smem[25920];
    unsigned short* xs = smem;
    unsigned short* im = smem + 19440;
    float* part = (float*)(smem + 24640);

    const int tid  = threadIdx.x;
    const int lane = tid & 63;
    const int wave = tid >> 6;
    const int b    = blockIdx.x / 3;
    const int pd   = blockIdx.x % 3;
    const int d0   = pd * 4;

    // ---- Phase A: stage x[b,:,d0..d0+5,0..29,0..31] -> f16 LDS ----
    for (int i = tid; i < 4320; i += 256) {          // 540 rows * 8 float4
        int q = i & 7, row = i >> 3;
        int hh = row % 30, rd = row / 30;
        int dd = rd % 6, cin = rd / 6;
        const float4 v = *(const float4*)(
            x + (((size_t)(b * CIN + cin) * DI + (d0 + dd)) * HI + hh) * WI + q * 4);
        ushort4 u;
        u.x = __builtin_bit_cast(unsigned short, (_Float16)v.x);
        u.y = __builtin_bit_cast(unsigned short, (_Float16)v.y);
        u.z = __builtin_bit_cast(unsigned short, (_Float16)v.z);
        u.w = __builtin_bit_cast(unsigned short, (_Float16)v.w);
        *(ushort4*)(xs + row * 36 + q * 4) = u;      // byte: row*72+q*8, 8B-aligned
    }
    // zero im2col K-slots 28..31 once (slot 27 written as zero by build; B-pad must be finite)
    for (int r = tid; r < 130; r += 256) {
        *(uint2*)(im + r * 40 + 28) = make_uint2(0u, 0u);
    }

    // per-lane loop-invariant fragments
    f16x8 wfrag[3];
    #pragma unroll
    for (int kw = 0; kw < 3; ++kw)
        wfrag[kw] = *(const f16x8*)(wtf + (kw * 64 + lane) * 8);
    const float4 bv = *(const float4*)(bias + ((lane >> 4) << 2));   // couts 4*(l>>4)+reg

    for (int ch = 0; ch < 7; ++ch) {                 // ch = pool-h cell (4 h rows)
        f32x4 pp0 = {0.f, 0.f, 0.f, 0.f};            // pool partial, tile wave+0
        f32x4 pp1 = {0.f, 0.f, 0.f, 0.f};            // pool partial, tile wave+4

        for (int d = 0; d < 4; ++d) {
            __syncthreads();                         // compute(prev) done before rebuild

            // ---- build im2col: one thread per row, 27 offset-folded u16 reads ----
            if (tid < 130) {
                const int h_loc = tid >> 5, wp = tid & 31;
                const int base = (d * 30 + ch * 4 + h_loc) * 36 + wp;
                unsigned short v[28];
                #pragma unroll
                for (int k = 0; k < 27; ++k) {
                    const int cin = k / 9, kd = (k % 9) / 3, kh = k % 3;
                    const int off = ((cin * 6 + kd) * 30 + kh) * 36;  // compile-time
                    v[k] = xs[base + off];
                }
                v[27] = 0;
                #pragma unroll
                for (int q = 0; q < 7; ++q) {
                    uint2 w;
                    w.x = (unsigned)v[4*q]   | ((unsigned)v[4*q+1] << 16);
                    w.y = (unsigned)v[4*q+2] | ((unsigned)v[4*q+3] << 16);
                    *(uint2*)(im + tid * 40 + q * 4) = w;
                }
            }
            __syncthreads();

            // ---- compute: 2 tiles/wave, 3 mfma each (kw row-shift) ----
            #pragma unroll
            for (int ti = 0; ti < 2; ++ti) {
                const int t = wave + ti * 4;
                const int rbase = t * 16 + (lane & 15);       // position row in im2col
                f32x4 acc = {0.f, 0.f, 0.f, 0.f};
                #pragma unroll
                for (int kw = 0; kw < 3; ++kw) {
                    f16x8 bfrag = *(const f16x8*)(im + (rbase + kw) * 40 + ((lane >> 4) << 3));
                    acc = __builtin_amdgcn_mfma_f32_16x16x32_f16(wfrag[kw], bfrag, acc, 0, 0, 0);
                }
                // lane holds couts {4*(l>>4)+0..3} of position t*16+(l&15)
                float y0 = acc[0] + bv.x, y1 = acc[1] + bv.y;
                float y2 = acc[2] + bv.z, y3 = acc[3] + bv.w;
                // softmax over 16 couts: 4 local + lanes l^16, l^32
                float m = fmaxf(fmaxf(y0, y1), fmaxf(y2, y3));
                m = fmaxf(m, __shfl_xor(m, 16));
                m = fmaxf(m, __shfl_xor(m, 32));
                float e0 = __expf(y0 - m), e1 = __expf(y1 - m);
                float e2 = __expf(y2 - m), e3 = __expf(y3 - m);
                float s = e0 + e1 + e2 + e3;
                s += __shfl_xor(s, 16);
                s += __shfl_xor(s, 32);
                float inv = 1.0f / s;
                float p0 = e0 * inv, p1 = e1 * inv, p2 = e2 * inv, p3 = e3 * inv;
                // pool over 4 consecutive w' (lanes l^1, l^2)
                p0 = fmaxf(p0, __shfl_xor(p0, 1)); p0 = fmaxf(p0, __shfl_xor(p0, 2));
                p1 = fmaxf(p1, __shfl_xor(p1, 1)); p1 = fmaxf(p1, __shfl_xor(p1, 2));
                p2 = fmaxf(p2, __shfl_xor(p2, 1)); p2 = fmaxf(p2, __shfl_xor(p2, 2));
                p3 = fmaxf(p3, __shfl_xor(p3, 1)); p3 = fmaxf(p3, __shfl_xor(p3, 2));
                if (ti == 0) {
                    pp0[0] = fmaxf(pp0[0], p0); pp0[1] = fmaxf(pp0[1], p1);
                    pp0[2] = fmaxf(pp0[2], p2); pp0[3] = fmaxf(pp0[3], p3);
                } else {
                    pp1[0] = fmaxf(pp1[0], p0); pp1[1] = fmaxf(pp1[1], p1);
                    pp1[2] = fmaxf(pp1[2], p2); pp1[3] = fmaxf(pp1[3], p3);
                }
            }
        } // d

        // ---- write pool partials (lanes l&3==0 hold pooled cells) ----
        __syncthreads();
        if ((lane & 3) == 0) {
            const int pw_loc = (lane & 15) >> 2;
            const int cg = (lane >> 4) << 2;
            {
                const int t = wave;
                *(f32x4*)(part + t * 80 + pw_loc * 20 + cg) = pp0;
            }
            {
                const int t = wave + 4;
                *(f32x4*)(part + t * 80 + pw_loc * 20 + cg) = pp1;
            }
        }
        __syncthreads();

        // ---- h-reduction over 4 tiles (same half), write out[b][c][pd][ch][pw] ----
        if (tid < 112) {
            const int c = tid & 15, pw = tid >> 4;        // pw 0..6
            const int half = pw >> 2, pl = pw & 3;
            float v =          part[(half    ) * 80 + pl * 20 + c];
            v = fmaxf(v,       part[(half + 2) * 80 + pl * 20 + c]);
            v = fmaxf(v,       part[(half + 4) * 80 + pl * 20 + c]);
            v = fmaxf(v,       part[(half + 6) * 80 + pl * 20 + c]);
            out[(((size_t)b * COUT + c) * 3 + pd) * 49 + ch * 7 + pw] = v;
        }
    } // ch
}

extern "C" void kernel_launch(void* const* d_in, const int* in_sizes, int n_in,
                              void* d_out, int out_size, void* d_ws, size_t ws_size,
                              hipStream_t stream) {
    const float* x    = (const float*)d_in[0];
    const float* W    = (const float*)d_in[1];
    const float* bias = (const float*)d_in[2];
    float* out = (float*)d_out;
    unsigned short* wtf = (unsigned short*)d_ws;   // 3*64*8 u16 = 3072 B

    prep<<<6, 256, 0, stream>>>(W, wtf);
    conv_sm_pool_mfma<<<BATCH * 3, 256, 0, stream>>>(x, wtf, bias, out);
}

// Round 4
// 39.650 us; speedup vs baseline: 7.4499x; 1.6768x over previous
//
#include <hip/hip_runtime.h>
#include <math.h>

#define BATCH 256
#define CIN   3
#define COUT  16
#define DI    16
#define HI    32
#define WI    32

typedef _Float16 f16;
typedef f16   f16x4 __attribute__((ext_vector_type(4)));
typedef f16   f16x8 __attribute__((ext_vector_type(8)));
typedef float f32x4 __attribute__((ext_vector_type(4)));

// LDS slab layout (f16 units): xs[dd][hh][w][ci]
//   ci stride 1 (cin 0..2 + zero pad), w stride 4, row stride 36*4=144 (288B),
//   plane stride 30*144=4320. 288B row ≡ 32 mod 128 -> conflict-free B reads.
#define ROWU   144
#define PLANEU 4320
#define XS_N   (6 * PLANEU)       // 25920 f16 = 51840 B -> 3 WG/CU
#define G8OFF  (2 * PLANEU + 2 * ROWU)   // (kd=2,kh=2) group-8 row offset = 8928

// ---------------------------------------------------------------------------
// Prep: build MFMA A-fragments from W[16][3][3][3][3] (fp32).
// K-order: k = g*4 + ci, g = kd*3+kh (groups 0..7 in main frags), ci = cin (3 real + pad).
// main:  wtf[kw][lane][j], j=0..7 -> k = 8*(lane>>4)+j    (3 kw variants)
// g8:    wtf[1536 + lane*8 + j]: k = 8*(lane>>4)+j; k<12 -> (kw=k>>2, ci=k&3) of group (2,2)
// ---------------------------------------------------------------------------
__global__ void prep(const float* __restrict__ W, unsigned short* __restrict__ wtf) {
    int e = blockIdx.x * 256 + threadIdx.x;       // 2048 tasks
    if (e >= 2048) return;
    float v = 0.f;
    if (e < 1536) {
        int kw = e >> 9, l = (e >> 3) & 63, j = e & 7;
        int c = l & 15;
        int k = ((l >> 4) << 3) + j;
        int g = k >> 2, ci = k & 3;
        if (ci < 3) v = W[(((c * 3 + ci) * 3 + g / 3) * 3 + g % 3) * 3 + kw];
        f16 h = (f16)v;
        wtf[(kw * 64 + l) * 8 + j] = __builtin_bit_cast(unsigned short, h);
    } else {
        int r = e - 1536, l = r >> 3, j = r & 7;
        int c = l & 15;
        int k = ((l >> 4) << 3) + j;
        if (k < 12) {
            int kw = k >> 2, ci = k & 3;
            if (ci < 3) v = W[(((c * 3 + ci) * 3 + 2) * 3 + 2) * 3 + kw];
        }
        f16 h = (f16)v;
        wtf[1536 + l * 8 + j] = __builtin_bit_cast(unsigned short, h);
    }
}

// ---------------------------------------------------------------------------
// Fused conv3d+bias+softmax(ch)+4^3 maxpool. One WG per (b,pd), 768 WGs,
// 3 WG/CU -> whole grid resident. ONE barrier total; each wave independently
// owns complete pool cells (tile cols = 4x4 (h,w) of one cell).
// ---------------------------------------------------------------------------
__global__ __launch_bounds__(256, 3) void conv_sm_pool_mfma(
    const float* __restrict__ x, const unsigned short* __restrict__ wtf,
    const float* __restrict__ bias, float* __restrict__ out)
{
    __shared__ __align__(16) f16 xs[XS_N];

    const int tid  = threadIdx.x;
    const int lane = tid & 63;
    const int wave = tid >> 6;
    const int b    = blockIdx.x / 3;
    const int pd   = blockIdx.x % 3;
    const int d0   = pd * 4;

    // ---- Phase A: stage x[b,:,d0..d0+5,0..29,0..31] -> cin-interleaved f16 LDS ----
    for (int i = tid; i < 1440; i += 256) {          // 6 dd * 30 hh * 8 wq
        int wq = i & 7;
        int r  = i >> 3;
        int hh = r % 30;
        int dd = r / 30;
        const float* px = x + ((size_t)b * 48 + (d0 + dd)) * 1024 + hh * 32 + wq * 4;
        float4 a0 = *(const float4*)(px);
        float4 a1 = *(const float4*)(px + 16384);
        float4 a2 = *(const float4*)(px + 32768);
        f16x8 p0, p1;
        p0[0] = (f16)a0.x; p0[1] = (f16)a1.x; p0[2] = (f16)a2.x; p0[3] = (f16)0.f;
        p0[4] = (f16)a0.y; p0[5] = (f16)a1.y; p0[6] = (f16)a2.y; p0[7] = (f16)0.f;
        p1[0] = (f16)a0.z; p1[1] = (f16)a1.z; p1[2] = (f16)a2.z; p1[3] = (f16)0.f;
        p1[4] = (f16)a0.w; p1[5] = (f16)a1.w; p1[6] = (f16)a2.w; p1[7] = (f16)0.f;
        f16* dst = xs + ((dd * 30 + hh) * 36 + wq * 4) * 4;
        *(f16x8*)(dst)     = p0;
        *(f16x8*)(dst + 8) = p1;
    }

    // per-lane invariants
    const int col = lane & 15;
    const int grp = lane >> 4;
    const int g0  = grp * 2;
    const int kd0 = g0 / 3,        kh0 = g0 % 3;
    const int kd1 = (g0 + 1) / 3,  kh1 = (g0 + 1) % 3;
    const int off1 = kd0 * PLANEU + kh0 * ROWU;
    const int off2 = kd1 * PLANEU + kh1 * ROWU;
    const int hl = col >> 2, wl = col & 3;
    const int spat = hl * ROWU + wl * 4;
    const int g8sel = (grp == 0) ? 0 : 8;            // grp0: kw0/1, others: kw2 (+garbage, A=0)

    const f16* wf = (const f16*)wtf;
    f16x8 wm[3];
    #pragma unroll
    for (int kw = 0; kw < 3; ++kw) wm[kw] = *(const f16x8*)(wf + (kw * 64 + lane) * 8);
    const f16x8 wg = *(const f16x8*)(wf + 1536 + lane * 8);
    const float4 bv = *(const float4*)(bias + grp * 4);  // couts 4*grp + 0..3

    __syncthreads();   // the only barrier

    for (int cell = wave; cell < 49; cell += 4) {    // cell = ch*7 + pw (one pool cell)
        const int ch = cell / 7;
        const int pw = cell - ch * 7;
        const f16* base = xs + (ch * 4) * ROWU + pw * 16 + spat;
        f32x4 pm = {0.f, 0.f, 0.f, 0.f};

        for (int d = 0; d < 4; ++d) {
            const f16* rb = base + d * PLANEU;
            f32x4 acc = {0.f, 0.f, 0.f, 0.f};
            f32x4 acg = {0.f, 0.f, 0.f, 0.f};

            // group-8 (kd=2,kh=2), all 3 kw packed into one MFMA's K slots
            f16x4 ga = *(const f16x4*)(rb + G8OFF + g8sel);
            f16x4 gb = *(const f16x4*)(rb + G8OFF + g8sel + 4);
            acg = __builtin_amdgcn_mfma_f32_16x16x32_f16(
                wg, __builtin_shufflevector(ga, gb, 0, 1, 2, 3, 4, 5, 6, 7), acg, 0, 0, 0);

            #pragma unroll
            for (int kw = 0; kw < 3; ++kw) {
                f16x4 b0 = *(const f16x4*)(rb + off1 + kw * 4);
                f16x4 b1 = *(const f16x4*)(rb + off2 + kw * 4);
                acc = __builtin_amdgcn_mfma_f32_16x16x32_f16(
                    wm[kw], __builtin_shufflevector(b0, b1, 0, 1, 2, 3, 4, 5, 6, 7),
                    acc, 0, 0, 0);
            }

            // softmax over 16 couts (4 local regs x 4 lane-groups via xor 16,32).
            // No max-subtraction: |y| <= ~51 -> exp safely inside fp32 range.
            float y0 = acc[0] + acg[0] + bv.x;
            float y1 = acc[1] + acg[1] + bv.y;
            float y2 = acc[2] + acg[2] + bv.z;
            float y3 = acc[3] + acg[3] + bv.w;
            float e0 = __expf(y0), e1 = __expf(y1), e2 = __expf(y2), e3 = __expf(y3);
            float s = (e0 + e1) + (e2 + e3);
            s += __shfl_xor(s, 16);
            s += __shfl_xor(s, 32);
            float inv = __builtin_amdgcn_rcpf(s);
            pm[0] = fmaxf(pm[0], e0 * inv);
            pm[1] = fmaxf(pm[1], e1 * inv);
            pm[2] = fmaxf(pm[2], e2 * inv);
            pm[3] = fmaxf(pm[3], e3 * inv);
        }

        // pool over the 16 positions of the cell (xor 1,2,4,8 within col group)
        #pragma unroll
        for (int m = 1; m <= 8; m <<= 1) {
            pm[0] = fmaxf(pm[0], __shfl_xor(pm[0], m));
            pm[1] = fmaxf(pm[1], __shfl_xor(pm[1], m));
            pm[2] = fmaxf(pm[2], __shfl_xor(pm[2], m));
            pm[3] = fmaxf(pm[3], __shfl_xor(pm[3], m));
        }

        if (col == 0) {
            float* po = out + ((size_t)b * COUT + grp * 4) * 147 + pd * 49 + cell;
            po[0]   = pm[0];
            po[147] = pm[1];
            po[294] = pm[2];
            po[441] = pm[3];
        }
    }
}

extern "C" void kernel_launch(void* const* d_in, const int* in_sizes, int n_in,
                              void* d_out, int out_size, void* d_ws, size_t ws_size,
                              hipStream_t stream) {
    const float* x    = (const float*)d_in[0];
    const float* W    = (const float*)d_in[1];
    const float* bias = (const float*)d_in[2];
    float* out = (float*)d_out;
    unsigned short* wtf = (unsigned short*)d_ws;   // 2048 u16 = 4096 B

    prep<<<8, 256, 0, stream>>>(W, wtf);
    conv_sm_pool_mfma<<<BATCH * 3, 256, 0, stream>>>(x, wtf, bias, out);
}

// Round 5
// 35.321 us; speedup vs baseline: 8.3629x; 1.1225x over previous
//
#include <hip/hip_runtime.h>
#include <math.h>

#define BATCH 256
#define CIN   3
#define COUT  16
#define DI    16
#define HI    32
#define WI    32

typedef _Float16 f16;
typedef f16   f16x4 __attribute__((ext_vector_type(4)));
typedef f16   f16x8 __attribute__((ext_vector_type(8)));
typedef float f32x4 __attribute__((ext_vector_type(4)));

// LDS slab (f16 units): xs[dd][hh][w][ci], ci stride 1 (3 cin + pad),
// w stride 4, row stride ROWU=144 (288B), plane stride PLANEU=4320.
#define ROWU   144
#define PLANEU 4320
#define XS_N   (6 * PLANEU)              // 25920 f16 = 51840 B -> 3 WG/CU
#define G8OFF  (2 * PLANEU + 2 * ROWU)   // (kd=2,kh=2) row offset

#define SV8(a, b) __builtin_shufflevector(a, b, 0, 1, 2, 3, 4, 5, 6, 7)

// ---------------------------------------------------------------------------
// Single fused kernel: conv3d + bias + channel-softmax + 4^3 maxpool.
// One WG per (b,pd); 768 WGs = 3 WG/CU, whole grid resident, ONE barrier.
// W A-fragments gathered per-lane straight from global (5KB, L2-broadcast) --
// no prep kernel, no serialized launch.
// ---------------------------------------------------------------------------
__global__ __launch_bounds__(256, 3) void conv_sm_pool_mfma(
    const float* __restrict__ x, const float* __restrict__ W,
    const float* __restrict__ bias, float* __restrict__ out)
{
    __shared__ __align__(16) f16 xs[XS_N];

    const int tid  = threadIdx.x;
    const int lane = tid & 63;
    const int wave = tid >> 6;
    const int b    = blockIdx.x / 3;
    const int pd   = blockIdx.x % 3;
    const int d0   = pd * 4;

    const int col = lane & 15;     // MFMA column / A-row (cout)
    const int q   = lane >> 4;     // lane group -> K slots [8q, 8q+8)

    // ---- W gather -> A-fragments (k = g*4 + ci, g = kd*3+kh; groups 2q,2q+1) ----
    // W[c][ci][kd][kh][kw]: offset = c*81 + ci*27 + 3*g + kw
    const float* wc = W + col * 81;
    const float* wq = wc + q * 6;                 // + 3*(2q)
    f16x8 wm[3];
    #pragma unroll
    for (int kw = 0; kw < 3; ++kw) {
        #pragma unroll
        for (int j = 0; j < 8; ++j) {
            const int ci = j & 3, jj = j >> 2;    // g = 2q + jj
            float v = (ci < 3) ? wq[ci * 27 + 3 * jj + kw] : 0.f;
            wm[kw][j] = (f16)v;
        }
    }
    // group-8 fragment (kd=2,kh=2): k = 8q+j; k<12 -> (kw=k>>2, ci=k&3)
    f16x8 wg = {};
    if (q == 0) {
        #pragma unroll
        for (int j = 0; j < 8; ++j) {
            const int ci = j & 3, kw = j >> 2;    // kw 0,1
            if (ci < 3) wg[j] = (f16)wc[ci * 27 + 24 + kw];
        }
    } else if (q == 1) {
        #pragma unroll
        for (int j = 0; j < 3; ++j) wg[j] = (f16)wc[j * 27 + 26];  // kw=2
    }
    const float4 bv = *(const float4*)(bias + q * 4);   // couts 4q+0..3

    // ---- Phase A: stage x[b,:,d0..d0+5,0..29,0..31] -> cin-interleaved f16 ----
    for (int i = tid; i < 1440; i += 256) {              // 6 dd * 30 hh * 8 wq
        int wqd = i & 7;
        int r   = i >> 3;
        int hh  = r % 30;
        int dd  = r / 30;
        const float* px = x + ((size_t)b * 48 + (d0 + dd)) * 1024 + hh * 32 + wqd * 4;
        float4 a0 = *(const float4*)(px);
        float4 a1 = *(const float4*)(px + 16384);
        float4 a2 = *(const float4*)(px + 32768);
        f16x8 p0, p1;
        p0[0] = (f16)a0.x; p0[1] = (f16)a1.x; p0[2] = (f16)a2.x; p0[3] = (f16)0.f;
        p0[4] = (f16)a0.y; p0[5] = (f16)a1.y; p0[6] = (f16)a2.y; p0[7] = (f16)0.f;
        p1[0] = (f16)a0.z; p1[1] = (f16)a1.z; p1[2] = (f16)a2.z; p1[3] = (f16)0.f;
        p1[4] = (f16)a0.w; p1[5] = (f16)a1.w; p1[6] = (f16)a2.w; p1[7] = (f16)0.f;
        f16* dst = xs + ((dd * 30 + hh) * 36 + wqd * 4) * 4;
        *(f16x8*)(dst)     = p0;
        *(f16x8*)(dst + 8) = p1;
    }

    // per-lane B-read invariants
    const int g0   = q * 2;
    const int off1 = (g0 / 3) * PLANEU + (g0 % 3) * ROWU;
    const int off2 = ((g0 + 1) / 3) * PLANEU + ((g0 + 1) % 3) * ROWU;
    const int hl = col >> 2, wl = col & 3;
    const int spat  = hl * ROWU + wl * 4;
    const int g8sel = (q == 0) ? 0 : 8;

    __syncthreads();   // the only barrier

    for (int cell = wave; cell < 49; cell += 4) {   // cell = ch*7 + pw
        const int ch = cell / 7;
        const int pw = cell - ch * 7;
        const f16* base = xs + (ch * 4) * ROWU + pw * 16 + spat;

        // ---- load ALL 4 d-slices' B fragments upfront (32 independent b64) ----
        f16x4 A1[4][3], A2[4][3], GA[4], GB[4];
        #pragma unroll
        for (int d = 0; d < 4; ++d) {
            const f16* rb = base + d * PLANEU;
            #pragma unroll
            for (int kw = 0; kw < 3; ++kw) {
                A1[d][kw] = *(const f16x4*)(rb + off1 + kw * 4);
                A2[d][kw] = *(const f16x4*)(rb + off2 + kw * 4);
            }
            GA[d] = *(const f16x4*)(rb + G8OFF + g8sel);
            GB[d] = *(const f16x4*)(rb + G8OFF + g8sel + 4);
        }

        // ---- 16 MFMAs: 4 independent chains of 4 ----
        f32x4 acc[4];
        #pragma unroll
        for (int d = 0; d < 4; ++d) {
            f32x4 a = {0.f, 0.f, 0.f, 0.f};
            a = __builtin_amdgcn_mfma_f32_16x16x32_f16(wm[0], SV8(A1[d][0], A2[d][0]), a, 0, 0, 0);
            a = __builtin_amdgcn_mfma_f32_16x16x32_f16(wm[1], SV8(A1[d][1], A2[d][1]), a, 0, 0, 0);
            a = __builtin_amdgcn_mfma_f32_16x16x32_f16(wm[2], SV8(A1[d][2], A2[d][2]), a, 0, 0, 0);
            a = __builtin_amdgcn_mfma_f32_16x16x32_f16(wg,   SV8(GA[d],    GB[d]),    a, 0, 0, 0);
            acc[d] = a;
        }

        // ---- 4 independent softmax chains; pool-over-d in registers ----
        f32x4 pm = {0.f, 0.f, 0.f, 0.f};
        #pragma unroll
        for (int d = 0; d < 4; ++d) {
            // |y| <= ~51 -> exp safe in fp32 without max-subtraction
            float y0 = acc[d][0] + bv.x, y1 = acc[d][1] + bv.y;
            float y2 = acc[d][2] + bv.z, y3 = acc[d][3] + bv.w;
            float e0 = __expf(y0), e1 = __expf(y1), e2 = __expf(y2), e3 = __expf(y3);
            float s = (e0 + e1) + (e2 + e3);
            s += __shfl_xor(s, 16);
            s += __shfl_xor(s, 32);
            float inv = __builtin_amdgcn_rcpf(s);
            pm[0] = fmaxf(pm[0], e0 * inv);
            pm[1] = fmaxf(pm[1], e1 * inv);
            pm[2] = fmaxf(pm[2], e2 * inv);
            pm[3] = fmaxf(pm[3], e3 * inv);
        }

        // ---- pool over the 16 positions of the cell ----
        #pragma unroll
        for (int m = 1; m <= 8; m <<= 1) {
            pm[0] = fmaxf(pm[0], __shfl_xor(pm[0], m));
            pm[1] = fmaxf(pm[1], __shfl_xor(pm[1], m));
            pm[2] = fmaxf(pm[2], __shfl_xor(pm[2], m));
            pm[3] = fmaxf(pm[3], __shfl_xor(pm[3], m));
        }

        if (col == 0) {
            float* po = out + ((size_t)b * COUT + q * 4) * 147 + pd * 49 + cell;
            po[0]   = pm[0];
            po[147] = pm[1];
            po[294] = pm[2];
            po[441] = pm[3];
        }
    }
}

extern "C" void kernel_launch(void* const* d_in, const int* in_sizes, int n_in,
                              void* d_out, int out_size, void* d_ws, size_t ws_size,
                              hipStream_t stream) {
    const float* x    = (const float*)d_in[0];
    const float* W    = (const float*)d_in[1];
    const float* bias = (const float*)d_in[2];
    float* out = (float*)d_out;

    conv_sm_pool_mfma<<<BATCH * 3, 256, 0, stream>>>(x, W, bias, out);
}